// Round 14
// baseline (3928.444 us; speedup 1.0000x reference)
//
#include <hip/hip_runtime.h>
#include <hip/hip_bf16.h>

static constexpr int H_ = 1024;
static constexpr int W_ = 1024;
static constexpr int STR_ = 16;
static constexpr int NH_ = 63;
static constexpr int NPATCH_ = NH_ * NH_;  // 3969

typedef short bf16x8 __attribute__((ext_vector_type(8)));
typedef short short4v __attribute__((ext_vector_type(4)));
typedef float f32x4 __attribute__((ext_vector_type(4)));

// ---------------------------------------------------------------------------
// R14 = R9 (proven best, 1337.8us) wrapped in a PERSISTENT-BLOCK loop.
// R13 (32x32 S3) was null -> instruction-count theory dead; reverted to R9's
// S3 (16x16, 120B stride: fewer bank conflicts 6.0e7 vs 7.8e7).
// Remaining unaccounted ~50% of cycles: one never-isolated candidate is the
// block drain/refill gap -- at 1 block/CU each CU idles between its ~8
// sequential blocks. Fix: grid = 252 blocks x 8 pairs each (252*8 = 2016
// exact; 252 <= 256 CUs -> all blocks resident entire kernel, zero refills).
// Body byte-identical to R9; pair-dependent scalars moved into the loop.
// Race audit: S0's next-iter writes (gap16 in h3_1 range, CP1 over swc) are
// all protected by the existing S4b->S5 barrier; no extra barrier needed.
//
// LDS (bytes), total 155200 (<160K; 1 block/CU):
//   sH1:   [0, 49200)        1025 rows x 48B ([pixel u*41+v][24ch bf16])
//   gap16: [49200, 49216)    ZEROED in S0
//   CP0:   [49216, 55360)    patch stage [2][32][48ch] rows 96B  (overlay)
//   CP1:   [55360, 61504)    same shifted left 1 col
//   sH2_0: [49216, 102136)   patch0 conv2 out: 441 rows x 120B
//   sH2_1: [102136, 155056)  patch1; head 16B ZEROED in S0
//   zrow:  [155056, 155192)  ZEROED in S0 (S3 junk-lane reads)
//   After S3: h3_0 [0,30000) h3_1 [30000,60000); sWc0/1 [60000/64096,+4096);
//             sp [68192,76384) 2x1024 f32
// ---------------------------------------------------------------------------
static constexpr int FGAP16 = 49200;
static constexpr int FCP0   = 49216;
static constexpr int FCP1   = 55360;
static constexpr int FSH2_0 = 49216;
static constexpr int FSH2SZ = 52920;
static constexpr int FSH2_1 = FSH2_0 + FSH2SZ;   // 102136
static constexpr int FZROW  = 155056;
static constexpr int FH3SZ  = 30000;
static constexpr int FSWC0  = 60000;
static constexpr int FSWC1  = 64096;
static constexpr int FSPA   = 68192;
static constexpr int FLDS   = 155200;
static constexpr int FNGRP  = 32;
static constexpr int FNPAIR = NH_ * FNGRP;       // 2016 pairs
static constexpr int FPPB   = 8;                 // pairs per block
static constexpr int FGRID  = FNPAIR / FPPB;     // 252 blocks (exact)

__device__ __forceinline__ unsigned short f2bf(float x) {
    __hip_bfloat16 b = __float2bfloat16(x);
    return __builtin_bit_cast(unsigned short, b);
}

__device__ __forceinline__ f32x4 mfma_bf16(bf16x8 a, bf16x8 b, f32x4 c) {
    return __builtin_amdgcn_mfma_f32_16x16x32_bf16(a, b, c, 0, 0, 0);
}

// fast ELU negative branch (R3: VALU cycles convert 1:1 to time here)
__device__ __forceinline__ float elu_neg(float x) { return __expf(x) - 1.f; }

__global__
__attribute__((amdgpu_flat_work_group_size(1024, 1024), amdgpu_waves_per_eu(4, 4)))
void fused_patch_kernel(
    const float* __restrict__ x1, const float* __restrict__ x2,
    const float* __restrict__ c1b, const float* __restrict__ c2b,
    const float* __restrict__ d2b, const float* __restrict__ d1b,
    const float* __restrict__ lin_w, const float* __restrict__ lin_b,
    const unsigned short* __restrict__ w1frag,
    const unsigned short* __restrict__ w2frag,
    const unsigned short* __restrict__ dw2frag,
    const float* __restrict__ dw1,
    float* __restrict__ recon)
{
    __shared__ alignas(16) char sbuf[FLDS];
    const int t   = (int)threadIdx.x;
    const int wv  = t >> 6, lane = t & 63;
    const int ln15 = lane & 15, quad = lane >> 4;

    // ---- pair-invariant preloads (hoisted out of the persistent loop) ----
    bf16x8 w1b[8];
    #pragma unroll
    for (int gg = 0; gg < 8; ++gg)
        w1b[gg] = *(const bf16x8*)(w1frag + (gg * 64 + lane) * 8);
    const float d1b0 = d1b[0];
    const f32x4 c1bq0 = *(const f32x4*)(c1b + quad * 4);
    f32x4 c1bq1 = (f32x4){0.f, 0.f, 0.f, 0.f};
    if (quad < 2) c1bq1 = *(const f32x4*)(c1b + 16 + quad * 4);
    const f32x4 d2bq0 = *(const f32x4*)(d2b + quad * 4);
    f32x4 d2bq1 = (f32x4){0.f, 0.f, 0.f, 0.f};
    if (quad < 2) d2bq1 = *(const f32x4*)(d2b + 16 + quad * 4);
    float dwp[4] = {0.f, 0.f, 0.f, 0.f};           // dw1 gather: pair-invariant
    {
        int r0 = t >> 5, c0 = t & 31;
        if (c0 < 24) {
            dwp[0] = dw1[(c0 * 2 + 0) * 64 + r0];
            dwp[1] = dw1[(c0 * 2 + 1) * 64 + r0];
        }
        int k1 = t + 1024, r1 = k1 >> 5, c1 = k1 & 31;
        if (c1 < 24) {
            dwp[2] = dw1[(c1 * 2 + 0) * 64 + r1];
            dwp[3] = dw1[(c1 * 2 + 1) * 64 + r1];
        }
    }

    for (int pr = 0; pr < FPPB; ++pr) {
        const int b   = (int)blockIdx.x * FPPB + pr;
        const int pi  = b / FNGRP, g = b - pi * FNGRP;
        const int pj0 = 2 * g;
        const int npat = (pj0 + 1 < NH_) ? 2 : 1;
        const int n0  = pi * NH_ + pj0;
        const int n1  = (npat == 2) ? (n0 + 1) : n0;
        const int Y0  = pi * STR_, X0 = pj0 * STR_;
        const float lw00 = lin_w[2 * n0], lw01 = lin_w[2 * n0 + 1];
        const float lw10 = lin_w[2 * n1], lw11 = lin_w[2 * n1 + 1];
        const float lbn0 = lin_b[n0], lbn1 = lin_b[n1];

        // ---- S0: zero hazard windows; stage union patch [2][32][48] x 2 copies ----
        if (t < 4)       ((float*)(sbuf + FGAP16))[t] = 0.f;
        else if (t < 8)  ((float*)(sbuf + FSH2_1))[t - 4] = 0.f;
        else if (t < 42) ((float*)(sbuf + FZROW))[t - 8] = 0.f;
        #pragma unroll
        for (int it = 0; it < 3; ++it) {
            int k = t + it * 1024;
            int d = (k >= 1536) ? 1 : 0;
            int rem = k - d * 1536;
            int y = rem / 48, x = rem - y * 48;
            int xg = X0 + x; if (xg > W_ - 1) xg = W_ - 1;
            unsigned short bb = f2bf((d ? x2 : x1)[(Y0 + y) * W_ + xg]);
            int row = (d * 32 + y) * 48;
            ((unsigned short*)(sbuf + FCP0))[row + x] = bb;
            if (x > 0) ((unsigned short*)(sbuf + FCP1))[row + x - 1] = bb;
        }
        __syncthreads();

        // ---- S1: conv1 union grid. M=1025 linear, N=32, K=128 ----
        for (int tl = wv; tl < 65; tl += 16) {
            const int rawm = tl * 16 + ln15;
            int m = rawm; if (m > 1024) m = 1024;
            int u = m / 41, v = m - u * 41;
            const char* cps = sbuf + ((v & 1) ? FCP1 : FCP0);
            const int vb2 = (v & ~1) * 2;
            f32x4 acc[2];
            acc[0] = (f32x4){0.f, 0.f, 0.f, 0.f};
            acc[1] = (f32x4){0.f, 0.f, 0.f, 0.f};
            #pragma unroll
            for (int kc = 0; kc < 4; ++kc) {
                const int idx8 = kc * 4 + quad;
                const int dd = idx8 >> 3, pp = idx8 & 7;
                const unsigned int* ap = (const unsigned int*)(cps + (dd * 32 + u + pp) * 96 + vb2);
                union { unsigned int u4[4]; bf16x8 v8; } af;
                af.u4[0] = ap[0]; af.u4[1] = ap[1]; af.u4[2] = ap[2]; af.u4[3] = ap[3];
                acc[0] = mfma_bf16(w1b[kc * 2 + 0], af.v8, acc[0]);
                acc[1] = mfma_bf16(w1b[kc * 2 + 1], af.v8, acc[1]);
            }
            if (rawm < 1025) {
                char* rowp = sbuf + rawm * 48;
                short4v p0;
                #pragma unroll
                for (int r = 0; r < 4; ++r) {
                    float hv = acc[0][r] + c1bq0[r];
                    hv = hv > 0.f ? hv : elu_neg(hv);
                    p0[r] = (short)f2bf(hv);
                }
                *(short4v*)(rowp + quad * 8) = p0;
                if (quad < 2) {
                    short4v p1;
                    #pragma unroll
                    for (int r = 0; r < 4; ++r) {
                        float hw = acc[1][r] + c1bq1[r];
                        hw = hw > 0.f ? hw : elu_neg(hw);
                        p1[r] = (short)f2bf(hw);
                    }
                    *(short4v*)(rowp + 32 + quad * 8) = p1;
                }
            }
        }
        __syncthreads();

        // ---- S2: conv2 both patches. 56 mtiles, 2 register passes ----
        auto s2pass = [&](int t0, int t1) {
            const bool h1ok = (t1 < 56);
            int ab[2], loc[2], Pp[2];
            #pragma unroll
            for (int i = 0; i < 2; ++i) {
                int tt = i ? (h1ok ? t1 : t0) : t0;
                int P = (tt >= 28) ? 1 : 0;
                int lc = tt - P * 28;
                int mm = lc * 16 + ln15; if (mm > 440) mm = 440;
                int y = mm / 21, x = mm - y * 21;
                ab[i] = (y * 41 + P * 16 + x) * 48;
                loc[i] = lc; Pp[i] = P;
            }
            f32x4 acc2[2][4];
            #pragma unroll
            for (int i = 0; i < 2; ++i)
                #pragma unroll
                for (int nt = 0; nt < 4; ++nt)
                    acc2[i][nt] = (f32x4){0.f, 0.f, 0.f, 0.f};
            const unsigned short* wb = w2frag + lane * 8;
            #pragma unroll
            for (int p = 0; p < 5; ++p) {
                #pragma unroll
                for (int q = 0; q < 5; ++q) {
                    const int tap  = p * 5 + q;
                    const int toff = (p * 41 + q) * 48;
                    bf16x8 bfr[4];
                    #pragma unroll
                    for (int nt = 0; nt < 4; ++nt)
                        bfr[nt] = *(const bf16x8*)(wb + (tap * 4 + nt) * 512);
                    {
                        bf16x8 a = *(const bf16x8*)(sbuf + ab[0] + toff + quad * 16);
                        #pragma unroll
                        for (int nt = 0; nt < 4; ++nt)
                            acc2[0][nt] = mfma_bf16(bfr[nt], a, acc2[0][nt]);
                    }
                    if (h1ok) {
                        bf16x8 a = *(const bf16x8*)(sbuf + ab[1] + toff + quad * 16);
                        #pragma unroll
                        for (int nt = 0; nt < 4; ++nt)
                            acc2[1][nt] = mfma_bf16(bfr[nt], a, acc2[1][nt]);
                    }
                }
            }
            #pragma unroll
            for (int i = 0; i < 2; ++i) {
                if (i == 1 && !h1ok) continue;
                int rawpix = loc[i] * 16 + ln15;
                if (rawpix < 441) {
                    char* rowp = sbuf + FSH2_0 + Pp[i] * FSH2SZ + rawpix * 120;
                    #pragma unroll
                    for (int nt = 0; nt < 4; ++nt) {
                        if (nt == 3 && quad == 3) continue;
                        const f32x4 bq = *(const f32x4*)(c2b + nt * 16 + quad * 4);
                        short4v pk;
                        #pragma unroll
                        for (int r = 0; r < 4; ++r)
                            pk[r] = (short)f2bf(fmaxf(acc2[i][nt][r] + bq[r], 0.f));
                        *(short4v*)(rowp + nt * 32 + quad * 8) = pk;
                    }
                }
            }
        };
        s2pass(wv, wv + 16);
        s2pass(wv + 32, wv + 48);
        __syncthreads();

        // ---- S3: deconv2 both patches. 80 mtiles / 16 waves = 5/wave ----
        f32x4 acc3[5][2];
        {
            #pragma unroll
            for (int i = 0; i < 5; ++i) {
                acc3[i][0] = (f32x4){0.f, 0.f, 0.f, 0.f};
                acc3[i][1] = (f32x4){0.f, 0.f, 0.f, 0.f};
            }
            int uarr[5], varr[5], aoff[5];
            bool mval[5];
            #pragma unroll
            for (int i = 0; i < 5; ++i) {
                int t5 = wv + 16 * i;
                int P = (t5 >= 40) ? 1 : 0;
                int lc = t5 - P * 40;
                int m = lc * 16 + ln15;
                mval[i] = (m < 625);
                int mc = mval[i] ? m : 0;
                uarr[i] = mc / 25; varr[i] = mc - uarr[i] * 25;
                aoff[i] = FSH2_0 + P * FSH2SZ + (uarr[i] * 21 + varr[i]) * 120;
            }
            const unsigned short* db = dw2frag + lane * 8;
            #pragma unroll
            for (int dy = 0; dy < 5; ++dy) {
                #pragma unroll
                for (int dx = 0; dx < 5; ++dx) {
                    const int tap = dy * 5 + dx;
                    const int t2o = (dy * 21 + dx) * 120;
                    bf16x8 bc0 = *(const bf16x8*)(db + tap * 2048);
                    bf16x8 bc1 = *(const bf16x8*)(db + tap * 2048 + 512);
                    bf16x8 bc2 = *(const bf16x8*)(db + tap * 2048 + 1024);
                    bf16x8 bc3 = *(const bf16x8*)(db + tap * 2048 + 1536);
                    #pragma unroll
                    for (int i = 0; i < 5; ++i) {
                        int yv = uarr[i] - dy, xv = varr[i] - dx;
                        bool ok = mval[i] && ((unsigned)yv < 21u) && ((unsigned)xv < 21u);
                        int ra = ok ? (aoff[i] - t2o) : FZROW;
                        const char* ap = sbuf + ra + quad * 16;
                        short4v lo0 = *(const short4v*)(ap);
                        short4v hi0 = *(const short4v*)(ap + 8);
                        bf16x8 a0 = __builtin_shufflevector(lo0, hi0, 0, 1, 2, 3, 4, 5, 6, 7);
                        acc3[i][0] = mfma_bf16(bc0, a0, acc3[i][0]);
                        acc3[i][1] = mfma_bf16(bc1, a0, acc3[i][1]);
                        short4v lo1 = *(const short4v*)(ap + 64);
                        short4v hi1 = *(const short4v*)(ap + 72);
                        bf16x8 a1 = __builtin_shufflevector(lo1, hi1, 0, 1, 2, 3, 4, 5, 6, 7);
                        acc3[i][0] = mfma_bf16(bc2, a1, acc3[i][0]);
                        acc3[i][1] = mfma_bf16(bc3, a1, acc3[i][1]);
                    }
                }
            }
        }
        __syncthreads();

        // ---- S4a: h3 = elu(acc3 + d2b); sWc both patches; zero sp ----
        float* sp = (float*)(sbuf + FSPA);
        {
            #pragma unroll
            for (int i = 0; i < 5; ++i) {
                int t5 = wv + 16 * i;
                int P = (t5 >= 40) ? 1 : 0;
                int lc = t5 - P * 40;
                int pix = lc * 16 + ln15;
                if (pix < 625) {
                    char* rowp = sbuf + P * FH3SZ + pix * 48;
                    short4v p0;
                    #pragma unroll
                    for (int r = 0; r < 4; ++r) {
                        float hv = acc3[i][0][r] + d2bq0[r];
                        hv = hv > 0.f ? hv : elu_neg(hv);
                        p0[r] = (short)f2bf(hv);
                    }
                    *(short4v*)(rowp + quad * 8) = p0;
                    if (quad < 2) {
                        short4v p1;
                        #pragma unroll
                        for (int r = 0; r < 4; ++r) {
                            float hw = acc3[i][1][r] + d2bq1[r];
                            hw = hw > 0.f ? hw : elu_neg(hw);
                            p1[r] = (short)f2bf(hw);
                        }
                        *(short4v*)(rowp + 32 + quad * 8) = p1;
                    }
                }
            }
        }
        {
            int r0 = t >> 5, c0 = t & 31;
            ((unsigned short*)(sbuf + FSWC0))[r0 * 32 + c0] = f2bf(lw00 * dwp[0] + lw01 * dwp[1]);
            ((unsigned short*)(sbuf + FSWC1))[r0 * 32 + c0] = f2bf(lw10 * dwp[0] + lw11 * dwp[1]);
            int k1 = t + 1024, r1 = k1 >> 5, c1 = k1 & 31;
            ((unsigned short*)(sbuf + FSWC0))[r1 * 32 + c1] = f2bf(lw00 * dwp[2] + lw01 * dwp[3]);
            ((unsigned short*)(sbuf + FSWC1))[r1 * 32 + c1] = f2bf(lw10 * dwp[2] + lw11 * dwp[3]);
        }
        sp[t] = 0.f; sp[t + 1024] = 0.f;
        __syncthreads();

        // ---- S4b: epilogue GEMM both patches, LDS-atomic scatter into sp ----
        {
            int qoff[4];
            #pragma unroll
            for (int r = 0; r < 4; ++r) {
                int qr = quad * 4 + r;
                qoff[r] = (qr >> 3) * 32 + (qr & 7);
            }
            #pragma unroll
            for (int i = 0; i < 5; ++i) {
                int t5 = wv + 16 * i;
                int P = (t5 >= 40) ? 1 : 0;
                int lc = t5 - P * 40;
                int rawpix = lc * 16 + ln15;
                bool pok = (rawpix < 625);
                int pc = pok ? rawpix : 624;
                bf16x8 a = *(const bf16x8*)(sbuf + P * FH3SZ + pc * 48 + quad * 16);
                const char* swc = sbuf + (P ? FSWC1 : FSWC0);
                float* spP = sp + P * 1024;
                int uvbase = (pc / 25) * 32 + (pc % 25);
                #pragma unroll
                for (int nt = 0; nt < 4; ++nt) {
                    bf16x8 wbv = *(const bf16x8*)(swc + (nt * 16 + ln15) * 64 + quad * 16);
                    f32x4 acc4 = (f32x4){0.f, 0.f, 0.f, 0.f};
                    acc4 = mfma_bf16(wbv, a, acc4);
                    if (pok) {
                        #pragma unroll
                        for (int r = 0; r < 4; ++r)
                            atomicAdd(&spP[uvbase + nt * 64 + qoff[r]], acc4[r]);
                    }
                }
            }
        }
        __syncthreads();

        // ---- S5: overlap-add into global recon ----
        {
            int yy = t >> 5, xx = t & 31;
            float ob0 = d1b0 * (lw00 + lw01) + lbn0;
            atomicAdd(&recon[(Y0 + yy) * W_ + X0 + xx], sp[t] + ob0);
            if (npat == 2) {
                float ob1 = d1b0 * (lw10 + lw11) + lbn1;
                atomicAdd(&recon[(Y0 + yy) * W_ + X0 + 16 + xx], sp[t + 1024] + ob1);
            }
        }
        // No loop-end barrier needed: next iter's S0 writes (gap16 in h3_1,
        // CP1 over swc, sH2_1 head) are all regions whose last readers (S4b)
        // are fenced by the S4b->S5 barrier above.
    }
}

// ---------------------------------------------------------------------------
// Prep (layouts unchanged; A/B frags share lane layout):
//  conv1:   i = (kc*2+nt)*512 + lane*8 + j -> n=nt*16+(lane&15), k=kc*32+(lane>>4)*8+j
//  conv2:   tap*2048 + nt*512 + lane*8 + j -> o=nt*16+ln15, c=quad*8+j (zeros o>=60, c>=24)
//  deconv2: tap*2048 + kc*1024 + nt*512 + lane*8 + j -> k=kc*32+quad*8+j, c=nt*16+ln15
//           (zeros k>=60, c>=24)
// ---------------------------------------------------------------------------
__global__ void prep_kernel(const float* __restrict__ c1w,
                            const float* __restrict__ c2w,
                            const float* __restrict__ d2w,
                            unsigned short* __restrict__ w1frag,
                            unsigned short* __restrict__ w2frag,
                            unsigned short* __restrict__ dw2frag)
{
    int i = blockIdx.x * blockDim.x + threadIdx.x;
    if (i < 51200) {
        int j = i & 7, lane = (i >> 3) & 63;
        int ln15 = lane & 15, quad = lane >> 4;
        if (i < 4096) {   // conv1
            int g = i >> 9;
            int kc = g >> 1, nt = g & 1;
            int nn = nt * 16 + ln15, k = kc * 32 + quad * 8 + j;
            w1frag[i] = f2bf((nn < 24) ? c1w[nn * 128 + k] : 0.f);
        }
        {   // conv2
            int nt = (i >> 9) & 3, tap = i >> 11;
            int o = nt * 16 + ln15, c = quad * 8 + j;
            float v = (o < 60 && c < 24) ? c2w[(o * 24 + c) * 25 + tap] : 0.f;
            w2frag[i] = f2bf(v);
        }
        {   // deconv2
            int nt = (i >> 9) & 1, kc = (i >> 10) & 1, tap = i >> 11;
            int k = kc * 32 + quad * 8 + j, c = nt * 16 + ln15;
            float v = (k < 60 && c < 24) ? d2w[(k * 24 + c) * 25 + tap] : 0.f;
            dw2frag[i] = f2bf(v);
        }
    }
}

__global__ void finalize_kernel(const float* __restrict__ x2,
                                const float* __restrict__ l1w,
                                float* __restrict__ out)
{
    int i = blockIdx.x * blockDim.x + threadIdx.x;
    if (i < H_ * W_) {
        float r = out[i];
        out[i] = x2[i] - r * l1w[0];
    }
}

extern "C" void kernel_launch(void* const* d_in, const int* in_sizes, int n_in,
                              void* d_out, int out_size, void* d_ws, size_t ws_size,
                              hipStream_t stream)
{
    const float* x1  = (const float*)d_in[0];
    const float* x2  = (const float*)d_in[1];
    const float* c1w = (const float*)d_in[2];
    const float* c1b = (const float*)d_in[3];
    const float* c2w = (const float*)d_in[4];
    const float* c2b = (const float*)d_in[5];
    const float* d2w = (const float*)d_in[6];
    const float* d2b = (const float*)d_in[7];
    const float* d1w = (const float*)d_in[8];
    const float* d1b = (const float*)d_in[9];
    const float* lw  = (const float*)d_in[10];
    const float* lb  = (const float*)d_in[11];
    const float* l1w = (const float*)d_in[12];

    float*          out     = (float*)d_out;
    unsigned short* w1frag  = (unsigned short*)d_ws;                      // 8192 B
    unsigned short* w2frag  = (unsigned short*)((char*)d_ws + 8192);      // 102400 B
    unsigned short* dw2frag = (unsigned short*)((char*)d_ws + 110592);    // 102400 B

    hipMemsetAsync(d_out, 0, (size_t)H_ * W_ * sizeof(float), stream);
    prep_kernel<<<100, 512, 0, stream>>>(c1w, c2w, d2w, w1frag, w2frag, dw2frag);
    fused_patch_kernel<<<FGRID, 1024, 0, stream>>>(x1, x2, c1b, c2b, d2b, d1b,
                                                   lw, lb, w1frag, w2frag, dw2frag,
                                                   d1w, out);
    finalize_kernel<<<(H_ * W_ + 255) / 256, 256, 0, stream>>>(x2, l1w, out);
}

// Round 15
// 1337.374 us; speedup vs baseline: 2.9374x; 2.9374x over previous
//
#include <hip/hip_runtime.h>
#include <hip/hip_bf16.h>

static constexpr int H_ = 1024;
static constexpr int W_ = 1024;
static constexpr int STR_ = 16;
static constexpr int NH_ = 63;
static constexpr int NPATCH_ = NH_ * NH_;  // 3969
static constexpr int NGRP_ = 32;           // ceil(63/2) column-pair groups
static constexpr int NBLK_ = NH_ * NGRP_;  // 2016 blocks, 2 patches each (last col group: 1)

typedef short bf16x8 __attribute__((ext_vector_type(8)));
typedef short short4v __attribute__((ext_vector_type(4)));
typedef float f32x4 __attribute__((ext_vector_type(4)));

// ---------------------------------------------------------------------------
// R15 = R9 restored byte-for-byte (proven best: 1337.8us, absmax 0.03125).
// Session summary (14 rounds of counter evidence):
//   WINS (serial-stream work removal, converts 1:1 to time):
//     expm1f->__expf (-72us, R3); spill elimination + operand-swapped MFMAs
//     (pixel on ln15, channel on quad*4+r; ds_write_b64 writebacks, 64-distinct
//     -addr S4b scatter) (-52us, R8); 2-patch merge + union conv1 grid (R7,
//     kept for layout).
//   REFUTED: sw pipelining x2 (compiler re-sinks loads at its 64-VGPR target),
//     LDS B-frag staging (R6), occupancy attrs (R9-null), K-split 2-block
//     (R10: launch_bounds(,8) split V/A file -> 1.2GB spills), de-fusion
//     (R12: HBM-bound, weights evicted from L2 by intermediate streams),
//     32x32 MFMA S3 (R13 null, +conflicts), persistent blocks (R14: hoisted
//     state + 64-VGPR budget -> 5.8GB spill traffic, 2.9x regression).
//   PLATEAU DIAGNOSIS: ~156us/block; no pipe >15%; residue = distributed
//     dependency latency at 4 waves/SIMD (LDS-capacity-bound), with the
//     compiler pinned at 64 VGPR. Breaking either constraint regressed.
//
// LDS (bytes), total 155200 (<160K; 1 block/CU):
//   sH1:   [0, 49200)        1025 rows x 48B ([pixel u*41+v][24ch bf16])
//   gap16: [49200, 49216)    ZEROED in S0
//   CP0:   [49216, 55360)    patch stage [2][32][48ch] rows 96B  (overlay)
//   CP1:   [55360, 61504)    same shifted left 1 col
//   sH2_0: [49216, 102136)   patch0 conv2 out: 441 rows x 120B
//   sH2_1: [102136, 155056)  patch1; head 16B ZEROED in S0
//   zrow:  [155056, 155192)  ZEROED in S0 (S3 junk-lane reads)
//   After S3: h3_0 [0,30000) h3_1 [30000,60000); sWc0/1 [60000/64096,+4096);
//             sp [68192,76384) 2x1024 f32
// ---------------------------------------------------------------------------
static constexpr int GAP16   = 49200;
static constexpr int CP0     = 49216;
static constexpr int CP1     = 55360;
static constexpr int SH2_0   = 49216;
static constexpr int SH2SZ   = 52920;
static constexpr int SH2_1   = SH2_0 + SH2SZ;      // 102136
static constexpr int ZROW    = 155056;
static constexpr int H3SZ    = 30000;
static constexpr int SWC0    = 60000;
static constexpr int SWC1    = 64096;
static constexpr int SPA     = 68192;
static constexpr int LDS_BYTES = 155200;

__device__ __forceinline__ unsigned short f2bf(float x) {
    __hip_bfloat16 b = __float2bfloat16(x);
    return __builtin_bit_cast(unsigned short, b);
}

__device__ __forceinline__ f32x4 mfma_bf16(bf16x8 a, bf16x8 b, f32x4 c) {
    return __builtin_amdgcn_mfma_f32_16x16x32_bf16(a, b, c, 0, 0, 0);
}

// fast ELU negative branch (R3: VALU cycles convert 1:1 to time here)
__device__ __forceinline__ float elu_neg(float x) { return __expf(x) - 1.f; }

__global__
__attribute__((amdgpu_flat_work_group_size(1024, 1024), amdgpu_waves_per_eu(4, 4)))
void fused_patch_kernel(
    const float* __restrict__ x1, const float* __restrict__ x2,
    const float* __restrict__ c1b, const float* __restrict__ c2b,
    const float* __restrict__ d2b, const float* __restrict__ d1b,
    const float* __restrict__ lin_w, const float* __restrict__ lin_b,
    const unsigned short* __restrict__ w1frag,   // conv1 B frags, bf16
    const unsigned short* __restrict__ w2frag,   // conv2 B frags, bf16
    const unsigned short* __restrict__ dw2frag,  // deconv2 B frags, bf16
    const float* __restrict__ dw1,               // raw deconv1_w (24,1,2,8,8)
    float* __restrict__ recon)                   // = d_out (atomic overlap-add)
{
    __shared__ alignas(16) char sbuf[LDS_BYTES];
    const int b   = blockIdx.x;
    const int pi  = b / NGRP_, g = b - pi * NGRP_;
    const int pj0 = 2 * g;
    const int npat = (pj0 + 1 < NH_) ? 2 : 1;
    const int n0  = pi * NH_ + pj0;
    const int n1  = (npat == 2) ? (n0 + 1) : n0;     // clamp for safe loads
    const int Y0  = pi * STR_, X0 = pj0 * STR_;
    const int t   = (int)threadIdx.x;
    const int wv  = t >> 6, lane = t & 63;
    const int ln15 = lane & 15, quad = lane >> 4;

    // ---- Top preloads (latency overlaps S0 staging) ----
    bf16x8 w1b[8];
    #pragma unroll
    for (int gg = 0; gg < 8; ++gg)
        w1b[gg] = *(const bf16x8*)(w1frag + (gg * 64 + lane) * 8);
    const float lw00 = lin_w[2 * n0], lw01 = lin_w[2 * n0 + 1];
    const float lw10 = lin_w[2 * n1], lw11 = lin_w[2 * n1 + 1];
    const float lbn0 = lin_b[n0], lbn1 = lin_b[n1];
    const float d1b0 = d1b[0];
    // channel-on-quad bias vectors (swapped D layout: ch = nt*16 + quad*4 + r)
    const f32x4 c1bq0 = *(const f32x4*)(c1b + quad * 4);            // ch 0..15
    f32x4 c1bq1 = (f32x4){0.f, 0.f, 0.f, 0.f};
    if (quad < 2) c1bq1 = *(const f32x4*)(c1b + 16 + quad * 4);     // ch 16..23
    const f32x4 d2bq0 = *(const f32x4*)(d2b + quad * 4);
    f32x4 d2bq1 = (f32x4){0.f, 0.f, 0.f, 0.f};
    if (quad < 2) d2bq1 = *(const f32x4*)(d2b + 16 + quad * 4);
    float dwp[4] = {0.f, 0.f, 0.f, 0.f};
    {
        int r0 = t >> 5, c0 = t & 31;
        if (c0 < 24) {
            dwp[0] = dw1[(c0 * 2 + 0) * 64 + r0];
            dwp[1] = dw1[(c0 * 2 + 1) * 64 + r0];
        }
        int k1 = t + 1024, r1 = k1 >> 5, c1 = k1 & 31;
        if (c1 < 24) {
            dwp[2] = dw1[(c1 * 2 + 0) * 64 + r1];
            dwp[3] = dw1[(c1 * 2 + 1) * 64 + r1];
        }
    }

    // ---- S0: zero hazard windows; stage union patch [2][32][48] -> 2 parity copies ----
    if (t < 4)       ((float*)(sbuf + GAP16))[t] = 0.f;
    else if (t < 8)  ((float*)(sbuf + SH2_1))[t - 4] = 0.f;     // sH2_1 head
    else if (t < 42) ((float*)(sbuf + ZROW))[t - 8] = 0.f;      // zero row + tail
    #pragma unroll
    for (int it = 0; it < 3; ++it) {
        int k = t + it * 1024;                 // 0..3071 = 2*32*48
        int d = (k >= 1536) ? 1 : 0;
        int rem = k - d * 1536;
        int y = rem / 48, x = rem - y * 48;
        int xg = X0 + x; if (xg > W_ - 1) xg = W_ - 1;   // npat==1 edge clamp
        unsigned short bb = f2bf((d ? x2 : x1)[(Y0 + y) * W_ + xg]);
        int row = (d * 32 + y) * 48;
        ((unsigned short*)(sbuf + CP0))[row + x] = bb;
        if (x > 0) ((unsigned short*)(sbuf + CP1))[row + x - 1] = bb;
    }
    __syncthreads();

    // ---- S1: conv1 union grid. M=1025 linear, N=32, K=128. Swapped MFMA:
    //      D pixel on ln15 -> writeback = 1-2 ds_write_b64 per lane. ----
    for (int tl = wv; tl < 65; tl += 16) {
        const int rawm = tl * 16 + ln15;
        int m = rawm; if (m > 1024) m = 1024;             // junk lanes clamp (read)
        int u = m / 41, v = m - u * 41;
        const char* cps = sbuf + ((v & 1) ? CP1 : CP0);
        const int vb2 = (v & ~1) * 2;
        f32x4 acc[2];
        acc[0] = (f32x4){0.f, 0.f, 0.f, 0.f};
        acc[1] = (f32x4){0.f, 0.f, 0.f, 0.f};
        #pragma unroll
        for (int kc = 0; kc < 4; ++kc) {
            const int idx8 = kc * 4 + quad;
            const int dd = idx8 >> 3, pp = idx8 & 7;
            const unsigned int* ap = (const unsigned int*)(cps + (dd * 32 + u + pp) * 96 + vb2);
            union { unsigned int u4[4]; bf16x8 v8; } af;
            af.u4[0] = ap[0]; af.u4[1] = ap[1]; af.u4[2] = ap[2]; af.u4[3] = ap[3];
            acc[0] = mfma_bf16(w1b[kc * 2 + 0], af.v8, acc[0]);   // SWAPPED
            acc[1] = mfma_bf16(w1b[kc * 2 + 1], af.v8, acc[1]);
        }
        if (rawm < 1025) {
            char* rowp = sbuf + rawm * 48;
            short4v p0;
            #pragma unroll
            for (int r = 0; r < 4; ++r) {
                float hv = acc[0][r] + c1bq0[r];
                hv = hv > 0.f ? hv : elu_neg(hv);
                p0[r] = (short)f2bf(hv);
            }
            *(short4v*)(rowp + quad * 8) = p0;                    // ch quad*4..+3
            if (quad < 2) {
                short4v p1;
                #pragma unroll
                for (int r = 0; r < 4; ++r) {
                    float hw = acc[1][r] + c1bq1[r];
                    hw = hw > 0.f ? hw : elu_neg(hw);
                    p1[r] = (short)f2bf(hw);
                }
                *(short4v*)(rowp + 32 + quad * 8) = p1;           // ch 16+quad*4..+3
            }
        }
    }
    __syncthreads();

    // ---- S2: conv2 both patches. 56 mtiles, 2 register passes. Swapped MFMA.
    //      Writeback: 3-4 ds_write_b64 per lane (was 16 u16 stores). ----
    auto s2pass = [&](int t0, int t1) {
        const bool h1 = (t1 < 56);
        int ab[2], loc[2], Pp[2];
        #pragma unroll
        for (int i = 0; i < 2; ++i) {
            int tt = i ? (h1 ? t1 : t0) : t0;
            int P = (tt >= 28) ? 1 : 0;
            int lc = tt - P * 28;
            int mm = lc * 16 + ln15; if (mm > 440) mm = 440;
            int y = mm / 21, x = mm - y * 21;
            ab[i] = (y * 41 + P * 16 + x) * 48;
            loc[i] = lc; Pp[i] = P;
        }
        f32x4 acc2[2][4];
        #pragma unroll
        for (int i = 0; i < 2; ++i)
            #pragma unroll
            for (int nt = 0; nt < 4; ++nt)
                acc2[i][nt] = (f32x4){0.f, 0.f, 0.f, 0.f};
        const unsigned short* wb = w2frag + lane * 8;
        #pragma unroll
        for (int p = 0; p < 5; ++p) {
            #pragma unroll
            for (int q = 0; q < 5; ++q) {
                const int tap  = p * 5 + q;
                const int toff = (p * 41 + q) * 48;
                bf16x8 bfr[4];
                #pragma unroll
                for (int nt = 0; nt < 4; ++nt)
                    bfr[nt] = *(const bf16x8*)(wb + (tap * 4 + nt) * 512);
                {
                    bf16x8 a = *(const bf16x8*)(sbuf + ab[0] + toff + quad * 16);
                    #pragma unroll
                    for (int nt = 0; nt < 4; ++nt)
                        acc2[0][nt] = mfma_bf16(bfr[nt], a, acc2[0][nt]);   // SWAPPED
                }
                if (h1) {
                    bf16x8 a = *(const bf16x8*)(sbuf + ab[1] + toff + quad * 16);
                    #pragma unroll
                    for (int nt = 0; nt < 4; ++nt)
                        acc2[1][nt] = mfma_bf16(bfr[nt], a, acc2[1][nt]);   // SWAPPED
                }
            }
        }
        // writeback: relu -> sH2 [pixel][60ch bf16]; pixel on ln15, ch = nt*16+quad*4+r
        #pragma unroll
        for (int i = 0; i < 2; ++i) {
            if (i == 1 && !h1) continue;
            int rawpix = loc[i] * 16 + ln15;
            if (rawpix < 441) {
                char* rowp = sbuf + SH2_0 + Pp[i] * SH2SZ + rawpix * 120;
                #pragma unroll
                for (int nt = 0; nt < 4; ++nt) {
                    if (nt == 3 && quad == 3) continue;          // ch 60..63 invalid
                    const f32x4 bq = *(const f32x4*)(c2b + nt * 16 + quad * 4);
                    short4v pk;
                    #pragma unroll
                    for (int r = 0; r < 4; ++r)
                        pk[r] = (short)f2bf(fmaxf(acc2[i][nt][r] + bq[r], 0.f));
                    *(short4v*)(rowp + nt * 32 + quad * 8) = pk;
                }
            }
        }
    };
    s2pass(wv, wv + 16);          // tiles 0..31
    s2pass(wv + 32, wv + 48);     // tiles 32..55 (t1 valid only wv<8)
    __syncthreads();

    // ---- S3: deconv2 both patches. 80 mtiles / 16 waves = 5/wave. Swapped
    //      MFMA; pixel already on ln15 for reads (unchanged). ----
    f32x4 acc3[5][2];
    {
        #pragma unroll
        for (int i = 0; i < 5; ++i) {
            acc3[i][0] = (f32x4){0.f, 0.f, 0.f, 0.f};
            acc3[i][1] = (f32x4){0.f, 0.f, 0.f, 0.f};
        }
        int uarr[5], varr[5], aoff[5];
        bool mval[5];
        #pragma unroll
        for (int i = 0; i < 5; ++i) {
            int t5 = wv + 16 * i;
            int P = (t5 >= 40) ? 1 : 0;
            int lc = t5 - P * 40;
            int m = lc * 16 + ln15;
            mval[i] = (m < 625);
            int mc = mval[i] ? m : 0;
            uarr[i] = mc / 25; varr[i] = mc - uarr[i] * 25;
            aoff[i] = SH2_0 + P * SH2SZ + (uarr[i] * 21 + varr[i]) * 120;
        }
        const unsigned short* db = dw2frag + lane * 8;
        #pragma unroll
        for (int dy = 0; dy < 5; ++dy) {
            #pragma unroll
            for (int dx = 0; dx < 5; ++dx) {
                const int tap = dy * 5 + dx;
                const int t2o = (dy * 21 + dx) * 120;
                bf16x8 bc0 = *(const bf16x8*)(db + tap * 2048);
                bf16x8 bc1 = *(const bf16x8*)(db + tap * 2048 + 512);
                bf16x8 bc2 = *(const bf16x8*)(db + tap * 2048 + 1024);
                bf16x8 bc3 = *(const bf16x8*)(db + tap * 2048 + 1536);
                #pragma unroll
                for (int i = 0; i < 5; ++i) {
                    int yv = uarr[i] - dy, xv = varr[i] - dx;
                    bool ok = mval[i] && ((unsigned)yv < 21u) && ((unsigned)xv < 21u);
                    int ra = ok ? (aoff[i] - t2o) : ZROW;
                    const char* ap = sbuf + ra + quad * 16;
                    short4v lo0 = *(const short4v*)(ap);
                    short4v hi0 = *(const short4v*)(ap + 8);
                    bf16x8 a0 = __builtin_shufflevector(lo0, hi0, 0, 1, 2, 3, 4, 5, 6, 7);
                    acc3[i][0] = mfma_bf16(bc0, a0, acc3[i][0]);   // SWAPPED
                    acc3[i][1] = mfma_bf16(bc1, a0, acc3[i][1]);
                    short4v lo1 = *(const short4v*)(ap + 64);
                    short4v hi1 = *(const short4v*)(ap + 72);
                    bf16x8 a1 = __builtin_shufflevector(lo1, hi1, 0, 1, 2, 3, 4, 5, 6, 7);
                    acc3[i][0] = mfma_bf16(bc2, a1, acc3[i][0]);   // SWAPPED
                    acc3[i][1] = mfma_bf16(bc3, a1, acc3[i][1]);
                }
            }
        }
    }
    __syncthreads();   // sH1/CP/sH2 dead from here

    // ---- S4a: h3_P = elu(acc3 + d2b); pixel on ln15 -> 1-2 b64 stores;
    //           sWc both patches; zero sp ----
    float* sp = (float*)(sbuf + SPA);
    {
        #pragma unroll
        for (int i = 0; i < 5; ++i) {
            int t5 = wv + 16 * i;
            int P = (t5 >= 40) ? 1 : 0;
            int lc = t5 - P * 40;
            int pix = lc * 16 + ln15;
            if (pix < 625) {
                char* rowp = sbuf + P * H3SZ + pix * 48;
                short4v p0;
                #pragma unroll
                for (int r = 0; r < 4; ++r) {
                    float hv = acc3[i][0][r] + d2bq0[r];
                    hv = hv > 0.f ? hv : elu_neg(hv);
                    p0[r] = (short)f2bf(hv);
                }
                *(short4v*)(rowp + quad * 8) = p0;
                if (quad < 2) {
                    short4v p1;
                    #pragma unroll
                    for (int r = 0; r < 4; ++r) {
                        float hw = acc3[i][1][r] + d2bq1[r];
                        hw = hw > 0.f ? hw : elu_neg(hw);
                        p1[r] = (short)f2bf(hw);
                    }
                    *(short4v*)(rowp + 32 + quad * 8) = p1;
                }
            }
        }
    }
    {
        int r0 = t >> 5, c0 = t & 31;
        ((unsigned short*)(sbuf + SWC0))[r0 * 32 + c0] = f2bf(lw00 * dwp[0] + lw01 * dwp[1]);
        ((unsigned short*)(sbuf + SWC1))[r0 * 32 + c0] = f2bf(lw10 * dwp[0] + lw11 * dwp[1]);
        int k1 = t + 1024, r1 = k1 >> 5, c1 = k1 & 31;
        ((unsigned short*)(sbuf + SWC0))[r1 * 32 + c1] = f2bf(lw00 * dwp[2] + lw01 * dwp[3]);
        ((unsigned short*)(sbuf + SWC1))[r1 * 32 + c1] = f2bf(lw10 * dwp[2] + lw11 * dwp[3]);
    }
    sp[t] = 0.f; sp[t + 1024] = 0.f;
    __syncthreads();

    // ---- S4b: epilogue GEMM both patches. Swapped MFMA: pixel on ln15 ->
    //           64 DISTINCT scatter addresses per wave-op (no same-addr RMW). ----
    {
        int qoff[4];
        #pragma unroll
        for (int r = 0; r < 4; ++r) {
            int qr = quad * 4 + r;
            qoff[r] = (qr >> 3) * 32 + (qr & 7);
        }
        #pragma unroll
        for (int i = 0; i < 5; ++i) {
            int t5 = wv + 16 * i;
            int P = (t5 >= 40) ? 1 : 0;
            int lc = t5 - P * 40;
            int rawpix = lc * 16 + ln15;
            bool pok = (rawpix < 625);
            int pc = pok ? rawpix : 624;
            bf16x8 a = *(const bf16x8*)(sbuf + P * H3SZ + pc * 48 + quad * 16);
            const char* swc = sbuf + (P ? SWC1 : SWC0);
            float* spP = sp + P * 1024;
            int uvbase = (pc / 25) * 32 + (pc % 25);
            #pragma unroll
            for (int nt = 0; nt < 4; ++nt) {
                bf16x8 wbv = *(const bf16x8*)(swc + (nt * 16 + ln15) * 64 + quad * 16);
                f32x4 acc4 = (f32x4){0.f, 0.f, 0.f, 0.f};
                acc4 = mfma_bf16(wbv, a, acc4);                   // SWAPPED
                if (pok) {
                    #pragma unroll
                    for (int r = 0; r < 4; ++r)
                        atomicAdd(&spP[uvbase + nt * 64 + qoff[r]], acc4[r]);
                }
            }
        }
    }
    __syncthreads();

    // ---- S5: overlap-add into global recon (phantom patch gated here only) ----
    {
        int yy = t >> 5, xx = t & 31;
        float ob0 = d1b0 * (lw00 + lw01) + lbn0;
        atomicAdd(&recon[(Y0 + yy) * W_ + X0 + xx], sp[t] + ob0);
        if (npat == 2) {
            float ob1 = d1b0 * (lw10 + lw11) + lbn1;
            atomicAdd(&recon[(Y0 + yy) * W_ + X0 + 16 + xx], sp[t + 1024] + ob1);
        }
    }
}

// ---------------------------------------------------------------------------
// Prep (layouts unchanged; A/B frags share lane layout so swap needs no change):
//  conv1:   i = (kc*2+nt)*512 + lane*8 + j -> n=nt*16+(lane&15), k=kc*32+(lane>>4)*8+j
//  conv2:   tap*2048 + nt*512 + lane*8 + j -> o=nt*16+ln15, c=quad*8+j (zeros o>=60, c>=24)
//  deconv2: tap*2048 + kc*1024 + nt*512 + lane*8 + j -> k=kc*32+quad*8+j, c=nt*16+ln15
//           (zeros k>=60, c>=24)
// ---------------------------------------------------------------------------
__global__ void prep_kernel(const float* __restrict__ c1w,
                            const float* __restrict__ c2w,
                            const float* __restrict__ d2w,
                            unsigned short* __restrict__ w1frag,
                            unsigned short* __restrict__ w2frag,
                            unsigned short* __restrict__ dw2frag)
{
    int i = blockIdx.x * blockDim.x + threadIdx.x;
    if (i < 51200) {
        int j = i & 7, lane = (i >> 3) & 63;
        int ln15 = lane & 15, quad = lane >> 4;
        if (i < 4096) {   // conv1
            int g = i >> 9;
            int kc = g >> 1, nt = g & 1;
            int nn = nt * 16 + ln15, k = kc * 32 + quad * 8 + j;
            w1frag[i] = f2bf((nn < 24) ? c1w[nn * 128 + k] : 0.f);
        }
        {   // conv2
            int nt = (i >> 9) & 3, tap = i >> 11;
            int o = nt * 16 + ln15, c = quad * 8 + j;
            float v = (o < 60 && c < 24) ? c2w[(o * 24 + c) * 25 + tap] : 0.f;
            w2frag[i] = f2bf(v);
        }
        {   // deconv2
            int nt = (i >> 9) & 1, kc = (i >> 10) & 1, tap = i >> 11;
            int k = kc * 32 + quad * 8 + j, c = nt * 16 + ln15;
            float v = (k < 60 && c < 24) ? d2w[(k * 24 + c) * 25 + tap] : 0.f;
            dw2frag[i] = f2bf(v);
        }
    }
}

__global__ void finalize_kernel(const float* __restrict__ x2,
                                const float* __restrict__ l1w,
                                float* __restrict__ out)
{
    int i = blockIdx.x * blockDim.x + threadIdx.x;
    if (i < H_ * W_) {
        float r = out[i];
        out[i] = x2[i] - r * l1w[0];
    }
}

extern "C" void kernel_launch(void* const* d_in, const int* in_sizes, int n_in,
                              void* d_out, int out_size, void* d_ws, size_t ws_size,
                              hipStream_t stream)
{
    const float* x1  = (const float*)d_in[0];
    const float* x2  = (const float*)d_in[1];
    const float* c1w = (const float*)d_in[2];
    const float* c1b = (const float*)d_in[3];
    const float* c2w = (const float*)d_in[4];
    const float* c2b = (const float*)d_in[5];
    const float* d2w = (const float*)d_in[6];
    const float* d2b = (const float*)d_in[7];
    const float* d1w = (const float*)d_in[8];
    const float* d1b = (const float*)d_in[9];
    const float* lw  = (const float*)d_in[10];
    const float* lb  = (const float*)d_in[11];
    const float* l1w = (const float*)d_in[12];

    float*          out     = (float*)d_out;
    unsigned short* w1frag  = (unsigned short*)d_ws;                      // 8192 B
    unsigned short* w2frag  = (unsigned short*)((char*)d_ws + 8192);      // 102400 B
    unsigned short* dw2frag = (unsigned short*)((char*)d_ws + 110592);    // 102400 B

    hipMemsetAsync(d_out, 0, (size_t)H_ * W_ * sizeof(float), stream);
    prep_kernel<<<100, 512, 0, stream>>>(c1w, c2w, d2w, w1frag, w2frag, dw2frag);
    fused_patch_kernel<<<NBLK_, 1024, 0, stream>>>(x1, x2, c1b, c2b, d2b, d1b,
                                                   lw, lb, w1frag, w2frag, dw2frag,
                                                   d1w, out);
    finalize_kernel<<<(H_ * W_ + 255) / 256, 256, 0, stream>>>(x2, l1w, out);
}